// Round 5
// baseline (92.132 us; speedup 1.0000x reference)
//
#include <hip/hip_runtime.h>
#include <hip/hip_bf16.h>

#define N_ 32
#define C_ 128
#define H_ 56
#define W_ 56
#define K_ 256
#define HW_ (H_*W_)
#define HP_ 58   // padded spatial dim

typedef __attribute__((ext_vector_type(8))) __bf16 bf16x8;
typedef __attribute__((ext_vector_type(8))) unsigned short ushort8;
typedef __attribute__((ext_vector_type(4))) float f32x4;

typedef __attribute__((address_space(1))) const unsigned int g1_u32;
typedef __attribute__((address_space(3))) unsigned int l3_u32;

__device__ __forceinline__ void dma16(const void* g, void* l) {
    __builtin_amdgcn_global_load_lds((g1_u32*)g, (l3_u32*)l, 16, 0, 0);
}

__device__ __forceinline__ unsigned short f2bf(float f) {
    unsigned int u = __builtin_bit_cast(unsigned int, f);
    u += 0x7FFFu + ((u >> 16) & 1u);   // round-to-nearest-even
    return (unsigned short)(u >> 16);
}

// ---------------- weight repack: OIHW fp32 -> fragment-major bf16 ----------
// wp2[((tap*16 + kg)*4 + cc)*64 + lane][j]: k = kg*16+(lane&15), c = cc*32+(lane>>4)*8+j
__global__ void repack_w2_kernel(const float* __restrict__ w,
                                 unsigned short* __restrict__ wp2) {
    int o = blockIdx.x * 256 + threadIdx.x;
    if (o >= 9 * 16 * 4 * 64 * 8) return;
    int j   = o & 7;
    int l   = (o >> 3) & 63;
    int cc  = (o >> 9) & 3;
    int kg  = (o >> 11) & 15;
    int tap = o >> 15;
    int k = kg * 16 + (l & 15);
    int c = cc * 32 + (l >> 4) * 8 + j;
    wp2[o] = f2bf(w[(k * C_ + c) * 9 + tap]);
}

// ---------------- x prepack: NCHW fp32 -> padded NHWC bf16 -----------------
// x_pad[n][hp][wp][c], hp,wp in [0,58), zero halo ring. One block per (n,hp).
__global__ void pack_x_kernel(const float* __restrict__ x,
                              unsigned short* __restrict__ xp) {
    __shared__ unsigned short Lt[128 * 57];   // [c][w], stride 57
    const int t  = threadIdx.x;               // 256
    const int b  = blockIdx.x;                // n*58 + hp
    const int n  = b / HP_;
    const int hp = b - n * HP_;
    unsigned short* orow = xp + ((size_t)(n * HP_ + hp) * HP_) * 128;

    ushort8 z = {0, 0, 0, 0, 0, 0, 0, 0};
    if (hp == 0 || hp == HP_ - 1) {
        for (int u = t; u < 928; u += 256)
            *(ushort8*)(orow + u * 8) = z;
        return;
    }
    const int h = hp - 1;
    const float* src = x + ((size_t)n * C_ * HW_ + h * W_);
    #pragma unroll
    for (int k = 0; k < 28; ++k) {
        int idx = k * 256 + t;               // 7168 = 128c x 56w
        int c = idx / 56, w2 = idx - 56 * c;
        Lt[c * 57 + w2] = f2bf(src[c * HW_ + w2]);
    }
    __syncthreads();
    for (int u = t; u < 928; u += 256) {     // 58 wp x 16 c8
        int wp = u >> 4, c8 = u & 15;
        ushort8 v = z;
        if (wp >= 1 && wp <= 56) {
            #pragma unroll
            for (int j = 0; j < 8; ++j)
                v[j] = Lt[(c8 * 8 + j) * 57 + (wp - 1)];
        }
        *(ushort8*)(orow + u * 8) = v;
    }
}

// ---------------- main conv: implicit GEMM, DMA-staged B -------------------
// Block: 256 kout x 112 px (2 rows), 8 waves, wave tile 32x112 (mi=2,ni=7).
// LDS tile per chunk: [csub=4][col=232][8ch] bf16 = 928 16B-units (+96 pad).
// col = hh*58+ww; tap (r,s) -> compile-time byte offset (r*58+s)*16.
// B staged by global_load_lds (2/thread/chunk), double-buffered.
__launch_bounds__(512, 4)
__global__ void conv_mfma4_kernel(const unsigned short* __restrict__ xp,
                                  const unsigned short* __restrict__ wp2,
                                  const float* __restrict__ bias,
                                  float* __restrict__ out) {
    __shared__ __align__(16) unsigned char Xt[2][16384];

    const int t    = threadIdx.x;
    const int lane = t & 63;
    const int wid  = t >> 6;

    // bijective XCD swizzle (896 % 8 == 0)
    const int b    = blockIdx.x;
    const int orig = (b & 7) * 112 + (b >> 3);
    const int n    = orig / 28;
    const int rp   = orig - n * 28;
    const int h0   = rp * 2;

    const int lp = lane & 15;
    const int lk = lane >> 4;

    // B-fragment byte offsets within a buffer (tap adds (r*58+s)*16)
    int bunit[7];
    #pragma unroll
    for (int ni = 0; ni < 7; ++ni) {
        int p  = ni * 16 + lp;
        int hr = (p >= 56) ? 1 : 0;
        int pw = p - hr * 56;
        bunit[ni] = (lk * 232 + hr * HP_ + pw) * 16;
    }

    // staging geometry: slot s -> csub = s/232, col = s%232 (chunk-invariant)
    const unsigned short* g0;
    const unsigned short* g1;
    {
        int s0 = t;
        int cs0 = s0 / 232, col0 = s0 - 232 * cs0;
        int hh0 = col0 / HP_, ww0 = col0 - HP_ * hh0;
        g0 = xp + (((size_t)(n * HP_ + h0 + hh0) * HP_ + ww0) * 128 + cs0 * 8);
        int s1 = 512 + t;
        if (s1 < 928) {
            int cs1 = s1 / 232, col1 = s1 - 232 * cs1;
            int hh1 = col1 / HP_, ww1 = col1 - HP_ * hh1;
            g1 = xp + (((size_t)(n * HP_ + h0 + hh1) * HP_ + ww1) * 128 + cs1 * 8);
        } else {
            g1 = xp;   // dummy valid address; lands in pad slots, never read
        }
    }
    void* d0 = Xt[0] + wid * 1024;
    void* d1 = Xt[0] + 8192 + wid * 1024;

    f32x4 acc[2][7];
    #pragma unroll
    for (int mi = 0; mi < 2; ++mi)
        #pragma unroll
        for (int ni = 0; ni < 7; ++ni)
            acc[mi][ni] = (f32x4){0.f, 0.f, 0.f, 0.f};

    // prologue: DMA chunk 0 into buf 0
    dma16(g0, d0);
    dma16(g1, d1);
    asm volatile("s_waitcnt vmcnt(0)" ::: "memory");
    __syncthreads();

    const ushort8* W8 = (const ushort8*)wp2;

    for (int cc = 0; cc < 4; ++cc) {
        const int cur = cc & 1;

        if (cc < 3) {   // DMA next chunk into other buffer; in flight under MFMAs
            dma16(g0 + (cc + 1) * 32, (char*)Xt[cur ^ 1] + wid * 1024);
            dma16(g1 + (cc + 1) * 32, (char*)Xt[cur ^ 1] + 8192 + wid * 1024);
        }

        const int fb = (wid * 2 * 4 + cc) * 64 + lane;   // ushort8 idx, mi=0
        #pragma unroll
        for (int tap = 0; tap < 9; ++tap) {
            const int r    = tap / 3;
            const int s    = tap - 3 * r;
            const int toff = (r * HP_ + s) * 16;         // compile-time per tap

            bf16x8 a0 = __builtin_bit_cast(bf16x8, W8[tap * 4096 + fb]);
            bf16x8 a1 = __builtin_bit_cast(bf16x8, W8[tap * 4096 + fb + 256]);

            bf16x8 bfr[7];
            #pragma unroll
            for (int ni = 0; ni < 7; ++ni)
                bfr[ni] = __builtin_bit_cast(bf16x8,
                    *(const ushort8*)(Xt[cur] + bunit[ni] + toff));

            #pragma unroll
            for (int ni = 0; ni < 7; ++ni) {
                acc[0][ni] = __builtin_amdgcn_mfma_f32_16x16x32_bf16(a0, bfr[ni], acc[0][ni], 0, 0, 0);
                acc[1][ni] = __builtin_amdgcn_mfma_f32_16x16x32_bf16(a1, bfr[ni], acc[1][ni], 0, 0, 0);
            }
        }

        if (cc < 3) {
            asm volatile("s_waitcnt vmcnt(0)" ::: "memory");
            __syncthreads();
        }
    }

    // epilogue: bias + fp32 store
    #pragma unroll
    for (int mi = 0; mi < 2; ++mi) {
        #pragma unroll
        for (int j = 0; j < 4; ++j) {
            int kout = wid * 32 + mi * 16 + lk * 4 + j;
            float bv = bias[kout];
            float* op = out + ((n * K_ + kout) * H_ + h0) * W_;
            #pragma unroll
            for (int ni = 0; ni < 7; ++ni) {
                int p  = ni * 16 + lp;
                int hr = (p >= 56) ? 1 : 0;
                int pw = p - hr * 56;
                op[hr * W_ + pw] = acc[mi][ni][j] + bv;
            }
        }
    }
}

// ---------------- R4 fallback (reg-staged fp32 path) -----------------------
__launch_bounds__(256, 2)
__global__ void conv_mfma3_kernel(const float* __restrict__ x,
                                  const unsigned short* __restrict__ wp2,
                                  const float* __restrict__ bias,
                                  float* __restrict__ out) {
    __shared__ unsigned short Xt[2][232 * 40];
    const int t    = threadIdx.x;
    const int lane = t & 63;
    const int wid  = t >> 6;
    const int b    = blockIdx.x;
    const int orig = (b & 7) * 112 + (b >> 3);
    const int n    = orig / 28;
    const int rp   = orig - n * 28;
    const int h0   = rp * 2;
    const int lp = lane & 15;
    const int lk = lane >> 4;
    int bofs[7];
    #pragma unroll
    for (int ni = 0; ni < 7; ++ni) {
        int p  = ni * 16 + lp;
        int hr = (p >= 56) ? 1 : 0;
        int pw = p - hr * 56;
        bofs[ni] = (hr * 58 + pw) * 40 + lk * 8;
    }
    bool  ok[4], v928[4];
    const float* xq[4];
    int   ldsw[4];
    #pragma unroll
    for (int i = 0; i < 4; ++i) {
        int it = i * 256 + t;
        v928[i] = (it < 928);
        int itc  = v928[i] ? it : 0;
        int csub = (itc >= 232) + (itc >= 464) + (itc >= 696);
        int col  = itc - 232 * csub;
        int hh   = col / 58;
        int ww   = col - 58 * hh;
        int hin  = h0 + hh - 1;
        int win  = ww - 1;
        ok[i]   = v928[i] && (unsigned)hin < 56u && (unsigned)win < 56u;
        xq[i]   = x + (((n * C_ + csub * 8) * H_ + hin) * W_ + win);
        ldsw[i] = col * 40 + csub * 8;
    }
    float xv[4][8];
#define STAGE_LOAD(CH)                                                 \
    _Pragma("unroll")                                                  \
    for (int i = 0; i < 4; ++i)                                        \
        _Pragma("unroll")                                              \
        for (int j = 0; j < 8; ++j)                                    \
            xv[i][j] = ok[i] ? xq[i][((CH) * 32 + j) * HW_] : 0.f;
#define STAGE_WRITE(BUF)                                               \
    _Pragma("unroll")                                                  \
    for (int i = 0; i < 4; ++i)                                        \
        if (v928[i]) {                                                 \
            ushort8 v;                                                 \
            _Pragma("unroll")                                          \
            for (int j = 0; j < 8; ++j) v[j] = f2bf(xv[i][j]);         \
            *(ushort8*)(&Xt[BUF][ldsw[i]]) = v;                        \
        }
    f32x4 acc[4][7];
    #pragma unroll
    for (int mi = 0; mi < 4; ++mi)
        #pragma unroll
        for (int ni = 0; ni < 7; ++ni)
            acc[mi][ni] = (f32x4){0.f, 0.f, 0.f, 0.f};
    STAGE_LOAD(0)
    STAGE_WRITE(0)
    __syncthreads();
    const ushort8* W8 = (const ushort8*)wp2;
    for (int cc = 0; cc < 4; ++cc) {
        const int cur = cc & 1;
        if (cc < 3) { STAGE_LOAD(cc + 1) }
        const int tb = wid * 1024 + cc * 64 + lane;
        #pragma unroll
        for (int tap = 0; tap < 9; ++tap) {
            const int r    = tap / 3;
            const int s    = tap - 3 * r;
            const int toff = (r * 58 + s) * 40;
            bf16x8 a[4];
            #pragma unroll
            for (int mi = 0; mi < 4; ++mi)
                a[mi] = __builtin_bit_cast(bf16x8, W8[tap * 4096 + tb + mi * 256]);
            bf16x8 bfr[7];
            #pragma unroll
            for (int ni = 0; ni < 7; ++ni)
                bfr[ni] = __builtin_bit_cast(bf16x8,
                    *(const ushort8*)(&Xt[cur][bofs[ni] + toff]));
            #pragma unroll
            for (int ni = 0; ni < 7; ++ni)
                #pragma unroll
                for (int mi = 0; mi < 4; ++mi)
                    acc[mi][ni] = __builtin_amdgcn_mfma_f32_16x16x32_bf16(
                        a[mi], bfr[ni], acc[mi][ni], 0, 0, 0);
        }
        if (cc < 3) {
            STAGE_WRITE(cur ^ 1)
            __syncthreads();
        }
    }
    #pragma unroll
    for (int mi = 0; mi < 4; ++mi) {
        #pragma unroll
        for (int j = 0; j < 4; ++j) {
            int kout = wid * 64 + mi * 16 + lk * 4 + j;
            float bv = bias[kout];
            float* op = out + ((n * K_ + kout) * H_ + h0) * W_;
            #pragma unroll
            for (int ni = 0; ni < 7; ++ni) {
                int p  = ni * 16 + lp;
                int hr = (p >= 56) ? 1 : 0;
                int pw = p - hr * 56;
                op[hr * W_ + pw] = acc[mi][ni][j] + bv;
            }
        }
    }
#undef STAGE_LOAD
#undef STAGE_WRITE
}

__global__ void conv_naive_kernel(const float* __restrict__ x,
                                  const float* __restrict__ w,
                                  const float* __restrict__ b,
                                  float* __restrict__ out) {
    int idx = blockIdx.x * 256 + threadIdx.x;
    if (idx >= N_ * K_ * HW_) return;
    int pw = idx % 56; int tmp = idx / 56;
    int h  = tmp % 56; tmp /= 56;
    int k  = tmp % 256; int n = tmp / 256;
    float acc = b[k];
    for (int c = 0; c < C_; ++c)
        for (int r = 0; r < 3; ++r) {
            int hin = h + r - 1;
            if ((unsigned)hin >= 56u) continue;
            for (int s = 0; s < 3; ++s) {
                int win = pw + s - 1;
                if ((unsigned)win >= 56u) continue;
                acc += x[((n * C_ + c) * H_ + hin) * W_ + win] * w[(k * C_ + c) * 9 + r * 3 + s];
            }
        }
    out[idx] = acc;
}

extern "C" void kernel_launch(void* const* d_in, const int* in_sizes, int n_in,
                              void* d_out, int out_size, void* d_ws, size_t ws_size,
                              hipStream_t stream) {
    const float* x = (const float*)d_in[0];
    const float* w = (const float*)d_in[1];
    const float* b = (const float*)d_in[2];
    float* out = (float*)d_out;

    const size_t xp_bytes = (size_t)N_ * HP_ * HP_ * C_ * 2;              // 27,557,888
    const size_t wp_bytes = (size_t)9 * 16 * 4 * 64 * 8 * 2;              // 589,824

    if (ws_size >= xp_bytes + wp_bytes) {
        unsigned short* xpad = (unsigned short*)d_ws;
        unsigned short* wp2  = (unsigned short*)((char*)d_ws + xp_bytes);
        pack_x_kernel<<<N_ * HP_, 256, 0, stream>>>(x, xpad);
        repack_w2_kernel<<<(9 * 16 * 4 * 64 * 8 + 255) / 256, 256, 0, stream>>>(w, wp2);
        conv_mfma4_kernel<<<896, 512, 0, stream>>>(xpad, wp2, b, out);
    } else if (ws_size >= wp_bytes) {
        unsigned short* wp2 = (unsigned short*)d_ws;
        repack_w2_kernel<<<(9 * 16 * 4 * 64 * 8 + 255) / 256, 256, 0, stream>>>(w, wp2);
        conv_mfma3_kernel<<<896, 256, 0, stream>>>(x, wp2, b, out);
    } else {
        conv_naive_kernel<<<(N_ * K_ * HW_ + 255) / 256, 256, 0, stream>>>(x, w, b, out);
    }
}

// Round 6
// 91.754 us; speedup vs baseline: 1.0041x; 1.0041x over previous
//
#include <hip/hip_runtime.h>
#include <hip/hip_bf16.h>

#define N_ 32
#define C_ 128
#define H_ 56
#define W_ 56
#define K_ 256
#define HW_ (H_*W_)
#define HP_ 58   // padded spatial dim
#define PL_ 236  // LDS plane stride in 16B units (232 data + 4 pad, breaks bank alias)

typedef __attribute__((ext_vector_type(8))) __bf16 bf16x8;
typedef __attribute__((ext_vector_type(8))) unsigned short ushort8;
typedef __attribute__((ext_vector_type(4))) float f32x4;

typedef __attribute__((address_space(1))) const unsigned int g1_u32;
typedef __attribute__((address_space(3))) unsigned int l3_u32;

__device__ __forceinline__ void dma16(const void* g, void* l) {
    __builtin_amdgcn_global_load_lds((g1_u32*)g, (l3_u32*)l, 16, 0, 0);
}

__device__ __forceinline__ unsigned short f2bf(float f) {
    unsigned int u = __builtin_bit_cast(unsigned int, f);
    u += 0x7FFFu + ((u >> 16) & 1u);   // round-to-nearest-even
    return (unsigned short)(u >> 16);
}

// ---------------- weight repack: OIHW fp32 -> fragment-major bf16 ----------
// wp2[((tap*16 + kg)*4 + cc)*64 + lane][j]: k = kg*16+(lane&15), c = cc*32+(lane>>4)*8+j
__global__ void repack_w2_kernel(const float* __restrict__ w,
                                 unsigned short* __restrict__ wp2) {
    int o = blockIdx.x * 256 + threadIdx.x;
    if (o >= 9 * 16 * 4 * 64 * 8) return;
    int j   = o & 7;
    int l   = (o >> 3) & 63;
    int cc  = (o >> 9) & 3;
    int kg  = (o >> 11) & 15;
    int tap = o >> 15;
    int k = kg * 16 + (l & 15);
    int c = cc * 32 + (l >> 4) * 8 + j;
    wp2[o] = f2bf(w[(k * C_ + c) * 9 + tap]);
}

// ---------------- x prepack: NCHW fp32 -> padded NHWC bf16 -----------------
__global__ void pack_x_kernel(const float* __restrict__ x,
                              unsigned short* __restrict__ xp) {
    __shared__ unsigned short Lt[128 * 57];   // [c][w], stride 57
    const int t  = threadIdx.x;               // 256
    const int b  = blockIdx.x;                // n*58 + hp
    const int n  = b / HP_;
    const int hp = b - n * HP_;
    unsigned short* orow = xp + ((size_t)(n * HP_ + hp) * HP_) * 128;

    ushort8 z = {0, 0, 0, 0, 0, 0, 0, 0};
    if (hp == 0 || hp == HP_ - 1) {
        for (int u = t; u < 928; u += 256)
            *(ushort8*)(orow + u * 8) = z;
        return;
    }
    const int h = hp - 1;
    const float* src = x + ((size_t)n * C_ * HW_ + h * W_);
    #pragma unroll
    for (int k = 0; k < 28; ++k) {
        int idx = k * 256 + t;               // 7168 = 128c x 56w
        int c = idx / 56, w2 = idx - 56 * c;
        Lt[c * 57 + w2] = f2bf(src[c * HW_ + w2]);
    }
    __syncthreads();
    for (int u = t; u < 928; u += 256) {     // 58 wp x 16 c8
        int wp = u >> 4, c8 = u & 15;
        ushort8 v = z;
        if (wp >= 1 && wp <= 56) {
            #pragma unroll
            for (int j = 0; j < 8; ++j)
                v[j] = Lt[(c8 * 8 + j) * 57 + (wp - 1)];
        }
        *(ushort8*)(orow + u * 8) = v;
    }
}

// ---------------- main conv: implicit GEMM, mi=4, DMA-staged B -------------
// Block: 256 kout x 112 px (2 rows), 4 waves, wave tile 64x112 (mi=4,ni=7).
// LDS per buffer: 4 planes x 236 units x 16B (plane pad breaks bank alias).
// Thread->slot map: u = i*256+t, csub = u/236, col = u%236 (col>=232 masked).
// Tap (r,s) -> uniform byte offset (r*58+s)*16. One vmcnt(0)+barrier/chunk.
__launch_bounds__(256, 2)
__global__ void conv_mfma5_kernel(const unsigned short* __restrict__ xp,
                                  const unsigned short* __restrict__ wp2,
                                  const float* __restrict__ bias,
                                  float* __restrict__ out) {
    __shared__ __align__(16) unsigned char Xt[2][PL_ * 4 * 16];   // 2 x 15104 B

    const int t    = threadIdx.x;
    const int lane = t & 63;
    const int wid  = t >> 6;

    // bijective XCD swizzle (896 % 8 == 0)
    const int b    = blockIdx.x;
    const int orig = (b & 7) * 112 + (b >> 3);
    const int n    = orig / 28;
    const int rp   = orig - n * 28;
    const int h0   = rp * 2;

    const int lp = lane & 15;
    const int lk = lane >> 4;

    // B-fragment byte offsets (tap adds (r*58+s)*16)
    int bunit[7];
    #pragma unroll
    for (int ni = 0; ni < 7; ++ni) {
        int p  = ni * 16 + lp;
        int hr = (p >= 56) ? 1 : 0;
        int pw = p - hr * 56;
        bunit[ni] = (lk * PL_ + hr * HP_ + pw) * 16;
    }

    // staging geometry: 4 slots/thread, u = i*256+t -> (csub, col)
    const unsigned short* gsrc[4];
    bool gok[4];
    #pragma unroll
    for (int i = 0; i < 4; ++i) {
        int u    = i * 256 + t;
        int csub = u / PL_;
        int col  = u - PL_ * csub;
        gok[i]   = (csub < 4) && (col < 232);
        int csc  = gok[i] ? csub : 0;
        int colc = gok[i] ? col : 0;
        int hh   = colc / HP_;
        int ww   = colc - HP_ * hh;
        gsrc[i]  = xp + (((size_t)(n * HP_ + h0 + hh) * HP_ + ww) * 128 + csc * 8);
    }

    f32x4 acc[4][7];
    #pragma unroll
    for (int mi = 0; mi < 4; ++mi)
        #pragma unroll
        for (int ni = 0; ni < 7; ++ni)
            acc[mi][ni] = (f32x4){0.f, 0.f, 0.f, 0.f};

#define STAGE(CH, BUF)                                                     \
    _Pragma("unroll")                                                      \
    for (int i = 0; i < 4; ++i)                                            \
        if (gok[i])                                                        \
            dma16(gsrc[i] + (CH) * 32, Xt[BUF] + i * 4096 + wid * 1024);

    // prologue: DMA chunk 0 into buf 0
    STAGE(0, 0)
    asm volatile("s_waitcnt vmcnt(0)" ::: "memory");
    __syncthreads();

    const ushort8* W8 = (const ushort8*)wp2;

    for (int cc = 0; cc < 4; ++cc) {
        const int cur = cc & 1;

        if (cc < 3) { STAGE(cc + 1, cur ^ 1) }   // in flight under 252 MFMAs

        const int fb = (wid * 4 * 4 + cc) * 64 + lane;   // ushort8 idx, mi=0
        #pragma unroll
        for (int tap = 0; tap < 9; ++tap) {
            const int r    = tap / 3;
            const int s    = tap - 3 * r;
            const int toff = (r * HP_ + s) * 16;         // compile-time per tap

            bf16x8 a[4];
            #pragma unroll
            for (int mi = 0; mi < 4; ++mi)
                a[mi] = __builtin_bit_cast(bf16x8, W8[tap * 4096 + fb + mi * 256]);

            bf16x8 bfr[7];
            #pragma unroll
            for (int ni = 0; ni < 7; ++ni)
                bfr[ni] = __builtin_bit_cast(bf16x8,
                    *(const ushort8*)(Xt[cur] + bunit[ni] + toff));

            #pragma unroll
            for (int ni = 0; ni < 7; ++ni)
                #pragma unroll
                for (int mi = 0; mi < 4; ++mi)
                    acc[mi][ni] = __builtin_amdgcn_mfma_f32_16x16x32_bf16(
                        a[mi], bfr[ni], acc[mi][ni], 0, 0, 0);
        }

        if (cc < 3) {
            asm volatile("s_waitcnt vmcnt(0)" ::: "memory");
            __syncthreads();
        }
    }
#undef STAGE

    // epilogue: bias + fp32 store
    #pragma unroll
    for (int mi = 0; mi < 4; ++mi) {
        #pragma unroll
        for (int j = 0; j < 4; ++j) {
            int kout = wid * 64 + mi * 16 + lk * 4 + j;
            float bv = bias[kout];
            float* op = out + ((n * K_ + kout) * H_ + h0) * W_;
            #pragma unroll
            for (int ni = 0; ni < 7; ++ni) {
                int p  = ni * 16 + lp;
                int hr = (p >= 56) ? 1 : 0;
                int pw = p - hr * 56;
                op[hr * W_ + pw] = acc[mi][ni][j] + bv;
            }
        }
    }
}

// ---------------- fallback (reg-staged fp32 path, R4) ----------------------
__launch_bounds__(256, 2)
__global__ void conv_mfma3_kernel(const float* __restrict__ x,
                                  const unsigned short* __restrict__ wp2,
                                  const float* __restrict__ bias,
                                  float* __restrict__ out) {
    __shared__ unsigned short Xt[2][232 * 40];
    const int t    = threadIdx.x;
    const int lane = t & 63;
    const int wid  = t >> 6;
    const int b    = blockIdx.x;
    const int orig = (b & 7) * 112 + (b >> 3);
    const int n    = orig / 28;
    const int rp   = orig - n * 28;
    const int h0   = rp * 2;
    const int lp = lane & 15;
    const int lk = lane >> 4;
    int bofs[7];
    #pragma unroll
    for (int ni = 0; ni < 7; ++ni) {
        int p  = ni * 16 + lp;
        int hr = (p >= 56) ? 1 : 0;
        int pw = p - hr * 56;
        bofs[ni] = (hr * 58 + pw) * 40 + lk * 8;
    }
    bool  ok[4], v928[4];
    const float* xq[4];
    int   ldsw[4];
    #pragma unroll
    for (int i = 0; i < 4; ++i) {
        int it = i * 256 + t;
        v928[i] = (it < 928);
        int itc  = v928[i] ? it : 0;
        int csub = (itc >= 232) + (itc >= 464) + (itc >= 696);
        int col  = itc - 232 * csub;
        int hh   = col / 58;
        int ww   = col - 58 * hh;
        int hin  = h0 + hh - 1;
        int win  = ww - 1;
        ok[i]   = v928[i] && (unsigned)hin < 56u && (unsigned)win < 56u;
        xq[i]   = x + (((n * C_ + csub * 8) * H_ + hin) * W_ + win);
        ldsw[i] = col * 40 + csub * 8;
    }
    float xv[4][8];
#define STAGE_LOAD(CH)                                                 \
    _Pragma("unroll")                                                  \
    for (int i = 0; i < 4; ++i)                                        \
        _Pragma("unroll")                                              \
        for (int j = 0; j < 8; ++j)                                    \
            xv[i][j] = ok[i] ? xq[i][((CH) * 32 + j) * HW_] : 0.f;
#define STAGE_WRITE(BUF)                                               \
    _Pragma("unroll")                                                  \
    for (int i = 0; i < 4; ++i)                                        \
        if (v928[i]) {                                                 \
            ushort8 v;                                                 \
            _Pragma("unroll")                                          \
            for (int j = 0; j < 8; ++j) v[j] = f2bf(xv[i][j]);         \
            *(ushort8*)(&Xt[BUF][ldsw[i]]) = v;                        \
        }
    f32x4 acc[4][7];
    #pragma unroll
    for (int mi = 0; mi < 4; ++mi)
        #pragma unroll
        for (int ni = 0; ni < 7; ++ni)
            acc[mi][ni] = (f32x4){0.f, 0.f, 0.f, 0.f};
    STAGE_LOAD(0)
    STAGE_WRITE(0)
    __syncthreads();
    const ushort8* W8 = (const ushort8*)wp2;
    for (int cc = 0; cc < 4; ++cc) {
        const int cur = cc & 1;
        if (cc < 3) { STAGE_LOAD(cc + 1) }
        const int tb = wid * 1024 + cc * 64 + lane;
        #pragma unroll
        for (int tap = 0; tap < 9; ++tap) {
            const int r    = tap / 3;
            const int s    = tap - 3 * r;
            const int toff = (r * 58 + s) * 40;
            bf16x8 a[4];
            #pragma unroll
            for (int mi = 0; mi < 4; ++mi)
                a[mi] = __builtin_bit_cast(bf16x8, W8[tap * 4096 + tb + mi * 256]);
            bf16x8 bfr[7];
            #pragma unroll
            for (int ni = 0; ni < 7; ++ni)
                bfr[ni] = __builtin_bit_cast(bf16x8,
                    *(const ushort8*)(&Xt[cur][bofs[ni] + toff]));
            #pragma unroll
            for (int ni = 0; ni < 7; ++ni)
                #pragma unroll
                for (int mi = 0; mi < 4; ++mi)
                    acc[mi][ni] = __builtin_amdgcn_mfma_f32_16x16x32_bf16(
                        a[mi], bfr[ni], acc[mi][ni], 0, 0, 0);
        }
        if (cc < 3) {
            STAGE_WRITE(cur ^ 1)
            __syncthreads();
        }
    }
    #pragma unroll
    for (int mi = 0; mi < 4; ++mi) {
        #pragma unroll
        for (int j = 0; j < 4; ++j) {
            int kout = wid * 64 + mi * 16 + lk * 4 + j;
            float bv = bias[kout];
            float* op = out + ((n * K_ + kout) * H_ + h0) * W_;
            #pragma unroll
            for (int ni = 0; ni < 7; ++ni) {
                int p  = ni * 16 + lp;
                int hr = (p >= 56) ? 1 : 0;
                int pw = p - hr * 56;
                op[hr * W_ + pw] = acc[mi][ni][j] + bv;
            }
        }
    }
#undef STAGE_LOAD
#undef STAGE_WRITE
}

__global__ void conv_naive_kernel(const float* __restrict__ x,
                                  const float* __restrict__ w,
                                  const float* __restrict__ b,
                                  float* __restrict__ out) {
    int idx = blockIdx.x * 256 + threadIdx.x;
    if (idx >= N_ * K_ * HW_) return;
    int pw = idx % 56; int tmp = idx / 56;
    int h  = tmp % 56; tmp /= 56;
    int k  = tmp % 256; int n = tmp / 256;
    float acc = b[k];
    for (int c = 0; c < C_; ++c)
        for (int r = 0; r < 3; ++r) {
            int hin = h + r - 1;
            if ((unsigned)hin >= 56u) continue;
            for (int s = 0; s < 3; ++s) {
                int win = pw + s - 1;
                if ((unsigned)win >= 56u) continue;
                acc += x[((n * C_ + c) * H_ + hin) * W_ + win] * w[(k * C_ + c) * 9 + r * 3 + s];
            }
        }
    out[idx] = acc;
}

extern "C" void kernel_launch(void* const* d_in, const int* in_sizes, int n_in,
                              void* d_out, int out_size, void* d_ws, size_t ws_size,
                              hipStream_t stream) {
    const float* x = (const float*)d_in[0];
    const float* w = (const float*)d_in[1];
    const float* b = (const float*)d_in[2];
    float* out = (float*)d_out;

    const size_t xp_bytes = (size_t)N_ * HP_ * HP_ * C_ * 2;              // 27,557,888
    const size_t wp_bytes = (size_t)9 * 16 * 4 * 64 * 8 * 2;              // 589,824

    if (ws_size >= xp_bytes + wp_bytes) {
        unsigned short* xpad = (unsigned short*)d_ws;
        unsigned short* wp2  = (unsigned short*)((char*)d_ws + xp_bytes);
        pack_x_kernel<<<N_ * HP_, 256, 0, stream>>>(x, xpad);
        repack_w2_kernel<<<(9 * 16 * 4 * 64 * 8 + 255) / 256, 256, 0, stream>>>(w, wp2);
        conv_mfma5_kernel<<<896, 256, 0, stream>>>(xpad, wp2, b, out);
    } else if (ws_size >= wp_bytes) {
        unsigned short* wp2 = (unsigned short*)d_ws;
        repack_w2_kernel<<<(9 * 16 * 4 * 64 * 8 + 255) / 256, 256, 0, stream>>>(w, wp2);
        conv_mfma3_kernel<<<896, 256, 0, stream>>>(x, wp2, b, out);
    } else {
        conv_naive_kernel<<<(N_ * K_ * HW_ + 255) / 256, 256, 0, stream>>>(x, w, b, out);
    }
}

// Round 7
// 85.832 us; speedup vs baseline: 1.0734x; 1.0690x over previous
//
#include <hip/hip_runtime.h>
#include <hip/hip_bf16.h>

#define N_ 32
#define C_ 128
#define H_ 56
#define W_ 56
#define K_ 256
#define HW_ (H_*W_)
#define HP_ 58   // padded spatial dim
#define PL_ 234  // LDS plane stride in 16B units: 234*4 dwords % 32 = 8 -> groups at banks {0,8,16,24}

typedef __attribute__((ext_vector_type(8))) __bf16 bf16x8;
typedef __attribute__((ext_vector_type(8))) unsigned short ushort8;
typedef __attribute__((ext_vector_type(4))) float f32x4;

typedef __attribute__((address_space(1))) const unsigned int g1_u32;
typedef __attribute__((address_space(3))) unsigned int l3_u32;

__device__ __forceinline__ void dma16(const void* g, void* l) {
    __builtin_amdgcn_global_load_lds((g1_u32*)g, (l3_u32*)l, 16, 0, 0);
}

__device__ __forceinline__ unsigned short f2bf(float f) {
    unsigned int u = __builtin_bit_cast(unsigned int, f);
    u += 0x7FFFu + ((u >> 16) & 1u);   // round-to-nearest-even
    return (unsigned short)(u >> 16);
}

// ---------------- weight repack: OIHW fp32 -> fragment-major bf16 ----------
// wp2[((tap*16 + kg)*4 + cc)*64 + lane][j]: k = kg*16+(lane&15), c = cc*32+(lane>>4)*8+j
__global__ void repack_w2_kernel(const float* __restrict__ w,
                                 unsigned short* __restrict__ wp2) {
    int o = blockIdx.x * 256 + threadIdx.x;
    if (o >= 9 * 16 * 4 * 64 * 8) return;
    int j   = o & 7;
    int l   = (o >> 3) & 63;
    int cc  = (o >> 9) & 3;
    int kg  = (o >> 11) & 15;
    int tap = o >> 15;
    int k = kg * 16 + (l & 15);
    int c = cc * 32 + (l >> 4) * 8 + j;
    wp2[o] = f2bf(w[(k * C_ + c) * 9 + tap]);
}

// ---------------- x prepack: NCHW fp32 -> padded NHWC bf16 -----------------
__global__ void pack_x_kernel(const float* __restrict__ x,
                              unsigned short* __restrict__ xp) {
    __shared__ unsigned short Lt[128 * 57];   // [c][w], stride 57
    const int t  = threadIdx.x;               // 256
    const int b  = blockIdx.x;                // n*58 + hp
    const int n  = b / HP_;
    const int hp = b - n * HP_;
    unsigned short* orow = xp + ((size_t)(n * HP_ + hp) * HP_) * 128;

    ushort8 z = {0, 0, 0, 0, 0, 0, 0, 0};
    if (hp == 0 || hp == HP_ - 1) {
        for (int u = t; u < 928; u += 256)
            *(ushort8*)(orow + u * 8) = z;
        return;
    }
    const int h = hp - 1;
    const float* src = x + ((size_t)n * C_ * HW_ + h * W_);
    #pragma unroll
    for (int k = 0; k < 28; ++k) {
        int idx = k * 256 + t;               // 7168 = 128c x 56w
        int c = idx / 56, w2 = idx - 56 * c;
        Lt[c * 57 + w2] = f2bf(src[c * HW_ + w2]);
    }
    __syncthreads();
    for (int u = t; u < 928; u += 256) {     // 58 wp x 16 c8
        int wp = u >> 4, c8 = u & 15;
        ushort8 v = z;
        if (wp >= 1 && wp <= 56) {
            #pragma unroll
            for (int j = 0; j < 8; ++j)
                v[j] = Lt[(c8 * 8 + j) * 57 + (wp - 1)];
        }
        *(ushort8*)(orow + u * 8) = v;
    }
}

// ---------------- main conv: counted-vmcnt, 3-buffer DMA pipeline ----------
// Block: 256 kout x 112 px (2 rows), 4 waves, wave tile 64x112 (mi=4,ni=7).
// Buffers: 3 x 1024 units x 16B (data 936 units = 4 planes x 234; rest dump).
// Schedule per chunk: [MFMA taps] -> issue DMA(c+2) -> vmcnt(4) -> s_barrier.
// DMAs are the newest vmem ops at each wait -> prefetch stays in flight
// across barriers (T4). Raw s_barrier (no compiler vmcnt(0) drain).
__launch_bounds__(256, 2)
__global__ void conv_mfma6_kernel(const unsigned short* __restrict__ xp,
                                  const unsigned short* __restrict__ wp2,
                                  const float* __restrict__ bias,
                                  float* __restrict__ out) {
    __shared__ __align__(16) unsigned char Xt[3][16384];

    const int t    = threadIdx.x;
    const int lane = t & 63;
    const int wid  = t >> 6;

    // bijective XCD swizzle (896 % 8 == 0)
    const int b    = blockIdx.x;
    const int orig = (b & 7) * 112 + (b >> 3);
    const int n    = orig / 28;
    const int rp   = orig - n * 28;
    const int h0   = rp * 2;

    const int lp = lane & 15;
    const int lk = lane >> 4;

    // B-fragment byte offsets (tap adds (r*58+s)*16)
    int bunit[7];
    #pragma unroll
    for (int ni = 0; ni < 7; ++ni) {
        int p  = ni * 16 + lp;
        int hr = (p >= 56) ? 1 : 0;
        int pw = p - hr * 56;
        bunit[ni] = (lk * PL_ + hr * HP_ + pw) * 16;
    }

    // staging geometry: slot u = i*256+t -> unit u; logical (csub,col) = (u/PL_, u%PL_).
    // Invalid slots (csub>=4 or col>=232) get a clamped source (xp base); the
    // garbage lands in pad/dump units that are never read. Every wave issues
    // exactly 4 unmasked DMAs per chunk -> exact vmcnt counting.
    const unsigned short* gsrc[4];
    #pragma unroll
    for (int i = 0; i < 4; ++i) {
        int u    = i * 256 + t;
        int csub = u / PL_;
        int col  = u - PL_ * csub;
        bool ok  = (csub < 4) && (col < 232);
        int csc  = ok ? csub : 0;
        int colc = ok ? col : 0;
        int hh   = colc / HP_;
        int ww   = colc - HP_ * hh;
        gsrc[i]  = ok ? xp + (((size_t)(n * HP_ + h0 + hh) * HP_ + ww) * 128 + csc * 8)
                      : xp;
    }

    f32x4 acc[4][7];
    #pragma unroll
    for (int mi = 0; mi < 4; ++mi)
        #pragma unroll
        for (int ni = 0; ni < 7; ++ni)
            acc[mi][ni] = (f32x4){0.f, 0.f, 0.f, 0.f};

#define STAGE(CH, BUF)                                                     \
    _Pragma("unroll")                                                      \
    for (int i = 0; i < 4; ++i)                                            \
        dma16(gsrc[i] + (CH) * 32, Xt[BUF] + i * 4096 + wid * 1024);

    // prologue: DMA chunks 0,1 into bufs 0,1; wait for chunk 0 only (4 newest fly)
    STAGE(0, 0)
    STAGE(1, 1)
    asm volatile("s_waitcnt vmcnt(4)" ::: "memory");
    __builtin_amdgcn_s_barrier();

    const ushort8* W8 = (const ushort8*)wp2;

    #pragma unroll
    for (int cc = 0; cc < 4; ++cc) {
        const int cur = cc % 3;

        const int fb = (wid * 16 + cc) * 64 + lane;      // ushort8 idx, mi=0
        __builtin_amdgcn_s_setprio(1);
        #pragma unroll
        for (int tap = 0; tap < 9; ++tap) {
            const int r    = tap / 3;
            const int s    = tap - 3 * r;
            const int toff = (r * HP_ + s) * 16;         // compile-time per tap

            bf16x8 a[4];
            #pragma unroll
            for (int mi = 0; mi < 4; ++mi)
                a[mi] = __builtin_bit_cast(bf16x8, W8[tap * 4096 + fb + mi * 256]);

            bf16x8 bfr[7];
            #pragma unroll
            for (int ni = 0; ni < 7; ++ni)
                bfr[ni] = __builtin_bit_cast(bf16x8,
                    *(const ushort8*)(Xt[cur] + bunit[ni] + toff));

            #pragma unroll
            for (int ni = 0; ni < 7; ++ni)
                #pragma unroll
                for (int mi = 0; mi < 4; ++mi)
                    acc[mi][ni] = __builtin_amdgcn_mfma_f32_16x16x32_bf16(
                        a[mi], bfr[ni], acc[mi][ni], 0, 0, 0);
        }
        __builtin_amdgcn_s_setprio(0);

        if (cc < 2) { STAGE(cc + 2, (cc + 2) % 3) }      // newest vmem ops

        if (cc < 3) {
            if (cc < 2) asm volatile("s_waitcnt vmcnt(4)" ::: "memory");
            else        asm volatile("s_waitcnt vmcnt(0)" ::: "memory");
            __builtin_amdgcn_s_barrier();
        }
    }
#undef STAGE

    // epilogue: bias + fp32 store
    #pragma unroll
    for (int mi = 0; mi < 4; ++mi) {
        #pragma unroll
        for (int j = 0; j < 4; ++j) {
            int kout = wid * 64 + mi * 16 + lk * 4 + j;
            float bv = bias[kout];
            float* op = out + ((n * K_ + kout) * H_ + h0) * W_;
            #pragma unroll
            for (int ni = 0; ni < 7; ++ni) {
                int p  = ni * 16 + lp;
                int hr = (p >= 56) ? 1 : 0;
                int pw = p - hr * 56;
                op[hr * W_ + pw] = acc[mi][ni][j] + bv;
            }
        }
    }
}

// ---------------- fallback (reg-staged fp32 path) --------------------------
__launch_bounds__(256, 2)
__global__ void conv_mfma3_kernel(const float* __restrict__ x,
                                  const unsigned short* __restrict__ wp2,
                                  const float* __restrict__ bias,
                                  float* __restrict__ out) {
    __shared__ unsigned short Xt[2][232 * 40];
    const int t    = threadIdx.x;
    const int lane = t & 63;
    const int wid  = t >> 6;
    const int b    = blockIdx.x;
    const int orig = (b & 7) * 112 + (b >> 3);
    const int n    = orig / 28;
    const int rp   = orig - n * 28;
    const int h0   = rp * 2;
    const int lp = lane & 15;
    const int lk = lane >> 4;
    int bofs[7];
    #pragma unroll
    for (int ni = 0; ni < 7; ++ni) {
        int p  = ni * 16 + lp;
        int hr = (p >= 56) ? 1 : 0;
        int pw = p - hr * 56;
        bofs[ni] = (hr * 58 + pw) * 40 + lk * 8;
    }
    bool  ok[4], v928[4];
    const float* xq[4];
    int   ldsw[4];
    #pragma unroll
    for (int i = 0; i < 4; ++i) {
        int it = i * 256 + t;
        v928[i] = (it < 928);
        int itc  = v928[i] ? it : 0;
        int csub = (itc >= 232) + (itc >= 464) + (itc >= 696);
        int col  = itc - 232 * csub;
        int hh   = col / 58;
        int ww   = col - 58 * hh;
        int hin  = h0 + hh - 1;
        int win  = ww - 1;
        ok[i]   = v928[i] && (unsigned)hin < 56u && (unsigned)win < 56u;
        xq[i]   = x + (((n * C_ + csub * 8) * H_ + hin) * W_ + win);
        ldsw[i] = col * 40 + csub * 8;
    }
    float xv[4][8];
#define STAGE_LOAD(CH)                                                 \
    _Pragma("unroll")                                                  \
    for (int i = 0; i < 4; ++i)                                        \
        _Pragma("unroll")                                              \
        for (int j = 0; j < 8; ++j)                                    \
            xv[i][j] = ok[i] ? xq[i][((CH) * 32 + j) * HW_] : 0.f;
#define STAGE_WRITE(BUF)                                               \
    _Pragma("unroll")                                                  \
    for (int i = 0; i < 4; ++i)                                        \
        if (v928[i]) {                                                 \
            ushort8 v;                                                 \
            _Pragma("unroll")                                          \
            for (int j = 0; j < 8; ++j) v[j] = f2bf(xv[i][j]);         \
            *(ushort8*)(&Xt[BUF][ldsw[i]]) = v;                        \
        }
    f32x4 acc[4][7];
    #pragma unroll
    for (int mi = 0; mi < 4; ++mi)
        #pragma unroll
        for (int ni = 0; ni < 7; ++ni)
            acc[mi][ni] = (f32x4){0.f, 0.f, 0.f, 0.f};
    STAGE_LOAD(0)
    STAGE_WRITE(0)
    __syncthreads();
    const ushort8* W8 = (const ushort8*)wp2;
    for (int cc = 0; cc < 4; ++cc) {
        const int cur = cc & 1;
        if (cc < 3) { STAGE_LOAD(cc + 1) }
        const int tb = wid * 1024 + cc * 64 + lane;
        #pragma unroll
        for (int tap = 0; tap < 9; ++tap) {
            const int r    = tap / 3;
            const int s    = tap - 3 * r;
            const int toff = (r * 58 + s) * 40;
            bf16x8 a[4];
            #pragma unroll
            for (int mi = 0; mi < 4; ++mi)
                a[mi] = __builtin_bit_cast(bf16x8, W8[tap * 4096 + tb + mi * 256]);
            bf16x8 bfr[7];
            #pragma unroll
            for (int ni = 0; ni < 7; ++ni)
                bfr[ni] = __builtin_bit_cast(bf16x8,
                    *(const ushort8*)(&Xt[cur][bofs[ni] + toff]));
            #pragma unroll
            for (int ni = 0; ni < 7; ++ni)
                #pragma unroll
                for (int mi = 0; mi < 4; ++mi)
                    acc[mi][ni] = __builtin_amdgcn_mfma_f32_16x16x32_bf16(
                        a[mi], bfr[ni], acc[mi][ni], 0, 0, 0);
        }
        if (cc < 3) {
            STAGE_WRITE(cur ^ 1)
            __syncthreads();
        }
    }
    #pragma unroll
    for (int mi = 0; mi < 4; ++mi) {
        #pragma unroll
        for (int j = 0; j < 4; ++j) {
            int kout = wid * 64 + mi * 16 + lk * 4 + j;
            float bv = bias[kout];
            float* op = out + ((n * K_ + kout) * H_ + h0) * W_;
            #pragma unroll
            for (int ni = 0; ni < 7; ++ni) {
                int p  = ni * 16 + lp;
                int hr = (p >= 56) ? 1 : 0;
                int pw = p - hr * 56;
                op[hr * W_ + pw] = acc[mi][ni][j] + bv;
            }
        }
    }
#undef STAGE_LOAD
#undef STAGE_WRITE
}

__global__ void conv_naive_kernel(const float* __restrict__ x,
                                  const float* __restrict__ w,
                                  const float* __restrict__ b,
                                  float* __restrict__ out) {
    int idx = blockIdx.x * 256 + threadIdx.x;
    if (idx >= N_ * K_ * HW_) return;
    int pw = idx % 56; int tmp = idx / 56;
    int h  = tmp % 56; tmp /= 56;
    int k  = tmp % 256; int n = tmp / 256;
    float acc = b[k];
    for (int c = 0; c < C_; ++c)
        for (int r = 0; r < 3; ++r) {
            int hin = h + r - 1;
            if ((unsigned)hin >= 56u) continue;
            for (int s = 0; s < 3; ++s) {
                int win = pw + s - 1;
                if ((unsigned)win >= 56u) continue;
                acc += x[((n * C_ + c) * H_ + hin) * W_ + win] * w[(k * C_ + c) * 9 + r * 3 + s];
            }
        }
    out[idx] = acc;
}

extern "C" void kernel_launch(void* const* d_in, const int* in_sizes, int n_in,
                              void* d_out, int out_size, void* d_ws, size_t ws_size,
                              hipStream_t stream) {
    const float* x = (const float*)d_in[0];
    const float* w = (const float*)d_in[1];
    const float* b = (const float*)d_in[2];
    float* out = (float*)d_out;

    const size_t xp_bytes = (size_t)N_ * HP_ * HP_ * C_ * 2;              // 27,557,888
    const size_t wp_bytes = (size_t)9 * 16 * 4 * 64 * 8 * 2;              // 589,824

    if (ws_size >= xp_bytes + wp_bytes) {
        unsigned short* xpad = (unsigned short*)d_ws;
        unsigned short* wp2  = (unsigned short*)((char*)d_ws + xp_bytes);
        pack_x_kernel<<<N_ * HP_, 256, 0, stream>>>(x, xpad);
        repack_w2_kernel<<<(9 * 16 * 4 * 64 * 8 + 255) / 256, 256, 0, stream>>>(w, wp2);
        conv_mfma6_kernel<<<896, 256, 0, stream>>>(xpad, wp2, b, out);
    } else if (ws_size >= wp_bytes) {
        unsigned short* wp2 = (unsigned short*)d_ws;
        repack_w2_kernel<<<(9 * 16 * 4 * 64 * 8 + 255) / 256, 256, 0, stream>>>(w, wp2);
        conv_mfma3_kernel<<<896, 256, 0, stream>>>(x, wp2, b, out);
    } else {
        conv_naive_kernel<<<(N_ * K_ * HW_ + 255) / 256, 256, 0, stream>>>(x, w, b, out);
    }
}